// Round 1
// baseline (409.881 us; speedup 1.0000x reference)
//
#include <hip/hip_runtime.h>

#define IN_F   8192
#define OUT_F  14336
#define M_TOK  64
#define KP     (IN_F / 2)        // packed int32 per weight row = 4096
#define BN     64                // N-tile per block (4 waves x 16)
#define KSPLIT 4
#define KCHUNK (IN_F / KSPLIT)   // 2048
#define NBLK   (OUT_F / BN)      // 224

typedef __attribute__((ext_vector_type(8))) short bf16x8;   // 8 bf16 (4 VGPRs)
typedef __attribute__((ext_vector_type(4))) float f32x4;    // MFMA C/D frag

__device__ __forceinline__ unsigned short f2bf_rne(float f) {
    unsigned u = __builtin_bit_cast(unsigned, f);
    u += 0x7FFFu + ((u >> 16) & 1u);
    return (unsigned short)(u >> 16);
}

// Prep: x fp32 -> bf16 into workspace, and out[m][n] = bias[n] (d_out is poisoned).
__global__ __launch_bounds__(256) void qlin_prep(const float* __restrict__ x,
                                                 const float* __restrict__ bias,
                                                 unsigned short* __restrict__ xb,
                                                 float* __restrict__ out) {
    const int XV = (M_TOK * IN_F) / 4;    // 131072 float4 of x
    const int OV = (M_TOK * OUT_F) / 4;   // 229376 float4 of out
    int gid = blockIdx.x * 256 + threadIdx.x;
    if (gid < XV) {
        float4 v = reinterpret_cast<const float4*>(x)[gid];
        ushort4 o;
        o.x = f2bf_rne(v.x);
        o.y = f2bf_rne(v.y);
        o.z = f2bf_rne(v.z);
        o.w = f2bf_rne(v.w);
        reinterpret_cast<ushort4*>(xb)[gid] = o;
    } else {
        int og = gid - XV;
        if (og < OV) {
            float4 b = reinterpret_cast<const float4*>(bias)[og % (OUT_F / 4)];
            reinterpret_cast<float4*>(out)[og] = b;
        }
    }
}

// Unpack one packed int32 (one byte: lo nibble = even k, hi nibble = odd k)
// into two bf16 bit-patterns packed in one dword. Ints in [-8,7] are exact in bf16.
__device__ __forceinline__ int unpack2_bf16(int v) {
    int q0 = ((int)((unsigned)v << 28)) >> 28;   // even k
    int q1 = ((int)((unsigned)v << 24)) >> 28;   // odd  k
    float f0 = (float)q0;
    float f1 = (float)q1;
    unsigned u0 = __builtin_bit_cast(unsigned, f0);
    unsigned u1 = __builtin_bit_cast(unsigned, f1);
    return (int)((u0 >> 16) | (u1 & 0xFFFF0000u));
}

// GEMM: each wave computes 64(M) x 16(N); block = 4 waves = 64 N. K split 4-way,
// partials combined via fp32 atomicAdd into bias-initialized out.
__global__ __launch_bounds__(256) void qlin_gemm(const unsigned short* __restrict__ xb,
                                                 const int* __restrict__ wp,
                                                 const float* __restrict__ scales,
                                                 float* __restrict__ out) {
    const int wave = threadIdx.x >> 6;
    const int lane = threadIdx.x & 63;
    const int t = lane & 15;     // A: m-within-tile ; B: n ; C/D: col (n)
    const int q = lane >> 4;     // A/B: k = q*8+j    ; C/D: row base q*4

    const int nblk = blockIdx.x % NBLK;
    const int kblk = blockIdx.x / NBLK;

    const int n  = nblk * BN + wave * 16 + t;     // weight row / output col
    const int k0 = kblk * KCHUNK + q * 8;         // this lane's k base

    const int*            __restrict__ wptr = wp + n * KP + (k0 >> 1);
    const unsigned short* __restrict__ xptr = xb + t * IN_F + k0;

    f32x4 acc0 = {0.f, 0.f, 0.f, 0.f};
    f32x4 acc1 = acc0, acc2 = acc0, acc3 = acc0;

#pragma unroll 4
    for (int kk = 0; kk < KCHUNK; kk += 32) {
        // B fragment: 8 consecutive weights of row n = 4 consecutive packed int32 (16 B)
        int4 wv = *reinterpret_cast<const int4*>(wptr + (kk >> 1));
        // A fragments: 8 consecutive bf16 of x rows (mt*16 + t), L2-hot
        bf16x8 a0 = *reinterpret_cast<const bf16x8*>(xptr + kk);
        bf16x8 a1 = *reinterpret_cast<const bf16x8*>(xptr + 16 * IN_F + kk);
        bf16x8 a2 = *reinterpret_cast<const bf16x8*>(xptr + 32 * IN_F + kk);
        bf16x8 a3 = *reinterpret_cast<const bf16x8*>(xptr + 48 * IN_F + kk);

        int4 pk;
        pk.x = unpack2_bf16(wv.x);
        pk.y = unpack2_bf16(wv.y);
        pk.z = unpack2_bf16(wv.z);
        pk.w = unpack2_bf16(wv.w);
        bf16x8 b = __builtin_bit_cast(bf16x8, pk);

        acc0 = __builtin_amdgcn_mfma_f32_16x16x32_bf16(a0, b, acc0, 0, 0, 0);
        acc1 = __builtin_amdgcn_mfma_f32_16x16x32_bf16(a1, b, acc1, 0, 0, 0);
        acc2 = __builtin_amdgcn_mfma_f32_16x16x32_bf16(a2, b, acc2, 0, 0, 0);
        acc3 = __builtin_amdgcn_mfma_f32_16x16x32_bf16(a3, b, acc3, 0, 0, 0);
    }

    const float sc = scales[n];
    const int mrow = q * 4;
#pragma unroll
    for (int r = 0; r < 4; ++r) {
        atomicAdd(&out[(     mrow + r) * OUT_F + n], acc0[r] * sc);
        atomicAdd(&out[(16 + mrow + r) * OUT_F + n], acc1[r] * sc);
        atomicAdd(&out[(32 + mrow + r) * OUT_F + n], acc2[r] * sc);
        atomicAdd(&out[(48 + mrow + r) * OUT_F + n], acc3[r] * sc);
    }
}

extern "C" void kernel_launch(void* const* d_in, const int* in_sizes, int n_in,
                              void* d_out, int out_size, void* d_ws, size_t ws_size,
                              hipStream_t stream) {
    const float* x     = (const float*)d_in[0];
    const int*   wp    = (const int*)d_in[1];
    const float* sc    = (const float*)d_in[2];
    const float* bias  = (const float*)d_in[3];
    float* out = (float*)d_out;
    unsigned short* xb = (unsigned short*)d_ws;   // 64*8192*2 = 1 MB

    const int prep_items = (M_TOK * IN_F) / 4 + (M_TOK * OUT_F) / 4;  // 360448
    qlin_prep<<<(prep_items + 255) / 256, 256, 0, stream>>>(x, bias, xb, out);
    qlin_gemm<<<NBLK * KSPLIT, 256, 0, stream>>>(xb, wp, sc, out);
}